// Round 1
// baseline (1834.661 us; speedup 1.0000x reference)
//
#include <hip/hip_runtime.h>
#include <math.h>

#define N_NODES 100000
#define N_EDGES 1600000
#define FEAT 131
#define HID 128

__device__ __forceinline__ float geluf(float x) {
    return 0.5f * x * (1.0f + erff(x * 0.7071067811865475f));
}
__device__ __forceinline__ float leakyf(float x) {
    return x >= 0.0f ? x : 0.2f * x;
}
__device__ __forceinline__ float wave_reduce_max(float v) {
#pragma unroll
    for (int o = 32; o > 0; o >>= 1) v = fmaxf(v, __shfl_xor(v, o, 64));
    return v;
}
__device__ __forceinline__ float wave_reduce_sum(float v) {
#pragma unroll
    for (int o = 32; o > 0; o >>= 1) v += __shfl_xor(v, o, 64);
    return v;
}

// ---------------- GEMM: C[M x ncols] = act(A[M x K] @ B[K x ncols] + bias) ----------------
// 64x64 block tile, 256 threads, 4x4 micro-tile, K-tile 16. ACT: 0=none, 1=gelu.
template <int ACT>
__global__ __launch_bounds__(256) void gemm_tiled(
    const float* __restrict__ A, int lda, int M, int K,
    const float* __restrict__ B, int ldb,
    const float* __restrict__ bias,
    float* __restrict__ C, int ldc, int colOff,
    const int* __restrict__ rowIdx)
{
    __shared__ float As[16][68];  // [k][m], pad 68 keeps float4 alignment + bank spread
    __shared__ float Bs[16][64];  // [k][n]
    int tid = threadIdx.x;
    int m0 = blockIdx.x * 64;
    int n0 = blockIdx.y * 64;
    int tx = tid & 15, ty = tid >> 4;
    float acc[4][4] = {};

    for (int k0 = 0; k0 < K; k0 += 16) {
#pragma unroll
        for (int i = 0; i < 4; ++i) {
            int idx = tid + i * 256;      // 0..1023 covers 64 rows x 16 k
            int r = idx >> 4, kk = idx & 15;
            int row = m0 + r, k = k0 + kk;
            As[kk][r] = (row < M && k < K) ? A[(size_t)row * lda + k] : 0.0f;
        }
#pragma unroll
        for (int i = 0; i < 4; ++i) {
            int idx = tid + i * 256;      // 16 k x 64 n
            int kk = idx >> 6, c = idx & 63;
            int k = k0 + kk;
            Bs[kk][c] = (k < K) ? B[(size_t)k * ldb + n0 + c] : 0.0f;
        }
        __syncthreads();
#pragma unroll
        for (int kk = 0; kk < 16; ++kk) {
            float4 a4 = *(const float4*)&As[kk][ty * 4];
            float4 b4 = *(const float4*)&Bs[kk][tx * 4];
            float av[4] = {a4.x, a4.y, a4.z, a4.w};
            float bv[4] = {b4.x, b4.y, b4.z, b4.w};
#pragma unroll
            for (int i = 0; i < 4; ++i)
#pragma unroll
                for (int j = 0; j < 4; ++j)
                    acc[i][j] = fmaf(av[i], bv[j], acc[i][j]);
        }
        __syncthreads();
    }

#pragma unroll
    for (int i = 0; i < 4; ++i) {
        int row = m0 + ty * 4 + i;
        if (row >= M) continue;
        int orow = rowIdx ? rowIdx[row] : row;
#pragma unroll
        for (int j = 0; j < 4; ++j) {
            int c = n0 + tx * 4 + j;
            float v = acc[i][j];
            if (bias) v += bias[c];
            if (ACT == 1) v = geluf(v);
            C[(size_t)orow * ldc + colOff + c] = v;
        }
    }
}

// node[ci[n]][128+j] = gelu(ars[n][j])
__global__ void ars_kernel(const float* __restrict__ ars, const int* __restrict__ ci,
                           float* __restrict__ node)
{
    int i = blockIdx.x * blockDim.x + threadIdx.x;
    if (i >= N_NODES * 3) return;
    int n = i / 3, j = i - n * 3;
    node[(size_t)ci[n] * FEAT + 128 + j] = geluf(ars[i]);
}

// ---------------- CSR build (by dst) ----------------
__global__ void hist_dst(const int* __restrict__ edges, int* __restrict__ deg)
{
    int e = blockIdx.x * blockDim.x + threadIdx.x;
    if (e < N_EDGES) atomicAdd(&deg[edges[2 * e + 1]], 1);
}

__global__ __launch_bounds__(1024) void scan_excl(const int* __restrict__ deg,
                                                  int* __restrict__ row_ptr)
{
    __shared__ int sd[1024];
    int tid = threadIdx.x;
    int base = 0;
    for (int start = 0; start < N_NODES; start += 1024) {
        int i = start + tid;
        int v = (i < N_NODES) ? deg[i] : 0;
        sd[tid] = v;
        __syncthreads();
        for (int off = 1; off < 1024; off <<= 1) {
            int t = (tid >= off) ? sd[tid - off] : 0;
            __syncthreads();
            sd[tid] += t;
            __syncthreads();
        }
        if (i < N_NODES) row_ptr[i] = base + sd[tid] - v;
        base += sd[1023];
        __syncthreads();
    }
    if (tid == 0) row_ptr[N_NODES] = base;
}

__global__ void copy_int(const int* __restrict__ src, int* __restrict__ dst, int n)
{
    int i = blockIdx.x * blockDim.x + threadIdx.x;
    if (i < n) dst[i] = src[i];
}

__global__ void scatter_csr(const int* __restrict__ edges, int* __restrict__ cursor,
                            int* __restrict__ csr_src)
{
    int e = blockIdx.x * blockDim.x + threadIdx.x;
    if (e >= N_EDGES) return;
    int s = edges[2 * e], d = edges[2 * e + 1];
    int pos = atomicAdd(&cursor[d], 1);
    csr_src[pos] = s;
}

// ---------------- attention scalars: a_s[n] = h[n].att_s, a_d[n] = h[n].att_d ----------------
__global__ __launch_bounds__(256) void attn_scores(
    const float* __restrict__ h, const float* __restrict__ atts,
    const float* __restrict__ attd, float* __restrict__ as_, float* __restrict__ ad_)
{
    int lane = threadIdx.x & 63;
    int node = blockIdx.x * 4 + (threadIdx.x >> 6);
    if (node >= N_NODES) return;
    float h0 = h[(size_t)node * HID + lane];
    float h1 = h[(size_t)node * HID + 64 + lane];
    float s = h0 * atts[lane] + h1 * atts[64 + lane];
    float d = h0 * attd[lane] + h1 * attd[64 + lane];
    s = wave_reduce_sum(s);
    d = wave_reduce_sum(d);
    if (lane == 0) { as_[node] = s; ad_[node] = d; }
}

// ---------------- GAT softmax-aggregate, one wave per dst node ----------------
// ACT: 0 = relu (layer0), 1 = gelu (layer1 -> d_out)
template <int ACT>
__global__ __launch_bounds__(256) void gat_aggregate(
    const float* __restrict__ h,
    const float* __restrict__ as_, const float* __restrict__ ad_,
    const int* __restrict__ row_ptr, const int* __restrict__ csr_src,
    const float* __restrict__ bias, float* __restrict__ outp)
{
    int lane = threadIdx.x & 63;
    int node = blockIdx.x * 4 + (threadIdx.x >> 6);
    if (node >= N_NODES) return;
    int start = row_ptr[node];
    int deg = row_ptr[node + 1] - start;
    float adn = ad_[node];
    float e_self = leakyf(as_[node] + adn);
    float acc0 = 0.0f, acc1 = 0.0f;
    float m, denom;

    if (deg <= 64) {   // true for essentially every node (E/N = 16 avg)
        int s = 0;
        float e = -INFINITY;
        if (lane < deg) {
            s = csr_src[start + lane];
            e = leakyf(as_[s] + adn);
        }
        m = fmaxf(wave_reduce_max(e), e_self);
        float w = (lane < deg) ? __expf(e - m) : 0.0f;
        denom = wave_reduce_sum(w) + __expf(e_self - m);
        for (int jj = 0; jj < deg; ++jj) {
            int sj = __shfl(s, jj, 64);
            float wj = __shfl(w, jj, 64);
            acc0 += wj * h[(size_t)sj * HID + lane];
            acc1 += wj * h[(size_t)sj * HID + 64 + lane];
        }
    } else {           // general fallback
        float lm = -INFINITY;
        for (int j = lane; j < deg; j += 64)
            lm = fmaxf(lm, leakyf(as_[csr_src[start + j]] + adn));
        m = fmaxf(wave_reduce_max(lm), e_self);
        float lsum = 0.0f;
        for (int j = lane; j < deg; j += 64)
            lsum += __expf(leakyf(as_[csr_src[start + j]] + adn) - m);
        denom = wave_reduce_sum(lsum) + __expf(e_self - m);
        for (int c0 = 0; c0 < deg; c0 += 64) {
            int j = c0 + lane;
            int s = 0;
            float w = 0.0f;
            if (j < deg) {
                s = csr_src[start + j];
                w = __expf(leakyf(as_[s] + adn) - m);
            }
            int cnt = min(64, deg - c0);
            for (int jj = 0; jj < cnt; ++jj) {
                int sj = __shfl(s, jj, 64);
                float wj = __shfl(w, jj, 64);
                acc0 += wj * h[(size_t)sj * HID + lane];
                acc1 += wj * h[(size_t)sj * HID + 64 + lane];
            }
        }
    }

    float wself = __expf(e_self - m);
    acc0 = (acc0 + wself * h[(size_t)node * HID + lane]) / denom;
    acc1 = (acc1 + wself * h[(size_t)node * HID + 64 + lane]) / denom;
    acc0 += bias[lane];
    acc1 += bias[64 + lane];
    if (ACT == 0) {
        acc0 = fmaxf(acc0, 0.0f);
        acc1 = fmaxf(acc1, 0.0f);
    } else {
        acc0 = geluf(acc0);
        acc1 = geluf(acc1);
    }
    outp[(size_t)node * HID + lane] = acc0;
    outp[(size_t)node * HID + 64 + lane] = acc1;
}

// ---------------- heads: pack [a0,a1,d0,d1] per node ----------------
__global__ __launch_bounds__(256) void head_proj(
    const float* __restrict__ outf,
    const float* __restrict__ Wa, const float* __restrict__ ba,
    const float* __restrict__ Wd, const float* __restrict__ bd,
    float* __restrict__ adp)
{
    int lane = threadIdx.x & 63;
    int node = blockIdx.x * 4 + (threadIdx.x >> 6);
    if (node >= N_NODES) return;
    float o0 = outf[(size_t)node * HID + lane];
    float o1 = outf[(size_t)node * HID + 64 + lane];
    float a0 = o0 * Wa[lane * 2] + o1 * Wa[(lane + 64) * 2];
    float a1 = o0 * Wa[lane * 2 + 1] + o1 * Wa[(lane + 64) * 2 + 1];
    float d0 = o0 * Wd[lane * 2] + o1 * Wd[(lane + 64) * 2];
    float d1 = o0 * Wd[lane * 2 + 1] + o1 * Wd[(lane + 64) * 2 + 1];
    a0 = wave_reduce_sum(a0);
    a1 = wave_reduce_sum(a1);
    d0 = wave_reduce_sum(d0);
    d1 = wave_reduce_sum(d1);
    if (lane == 0) {
        float4 v = make_float4(a0 + ba[0], a1 + ba[1], d0 + bd[0], d1 + bd[1]);
        ((float4*)adp)[node] = v;
    }
}

__global__ void edge_pred(const int* __restrict__ edges, const float* __restrict__ adp,
                          float* __restrict__ pred)
{
    int e = blockIdx.x * blockDim.x + threadIdx.x;
    if (e >= N_EDGES) return;
    int s = edges[2 * e], d = edges[2 * e + 1];
    float4 ps = ((const float4*)adp)[s];
    float4 pd = ((const float4*)adp)[d];
    pred[2 * e] = ps.x * pd.x + ps.y * pd.y;
    pred[2 * e + 1] = ps.z * pd.z + ps.w * pd.w;
}

extern "C" void kernel_launch(void* const* d_in, const int* in_sizes, int n_in,
                              void* d_out, int out_size, void* d_ws, size_t ws_size,
                              hipStream_t stream)
{
    const float* imgf = (const float*)d_in[0];
    const float* txtf = (const float*)d_in[1];
    const int* ci     = (const int*)d_in[2];
    // d_in[3] = gt_indices (unused)
    const int* edges  = (const int*)d_in[4];
    const float* ars  = (const float*)d_in[5];
    const float* Wi   = (const float*)d_in[6];
    const float* bi   = (const float*)d_in[7];
    const float* Wt   = (const float*)d_in[8];
    const float* bt   = (const float*)d_in[9];
    const float* W0   = (const float*)d_in[10];
    const float* as0  = (const float*)d_in[11];
    const float* ad0  = (const float*)d_in[12];
    const float* b0   = (const float*)d_in[13];
    const float* W1   = (const float*)d_in[14];
    const float* as1  = (const float*)d_in[15];
    const float* ad1  = (const float*)d_in[16];
    const float* b1   = (const float*)d_in[17];
    const float* Wa   = (const float*)d_in[18];
    const float* ba   = (const float*)d_in[19];
    const float* Wd   = (const float*)d_in[20];
    const float* bd   = (const float*)d_in[21];
    (void)in_sizes; (void)n_in; (void)out_size; (void)ws_size;

    float* out0 = (float*)d_out;                  // N x 128 (gelu'd layer-2 output)
    float* pred = out0 + (size_t)N_NODES * HID;   // E x 2

    char* ws = (char*)d_ws;
    size_t off = 0;
    auto alloc = [&](size_t bytes) -> void* {
        void* p = ws + off;
        off += (bytes + 255) & ~(size_t)255;
        return p;
    };
    float* node   = (float*)alloc((size_t)N_NODES * FEAT * 4);  // also reused as inter-layer h-buffer
    float* hA     = (float*)alloc((size_t)N_NODES * HID * 4);
    float* as_buf = (float*)alloc((size_t)N_NODES * 4);
    float* ad_buf = (float*)alloc((size_t)N_NODES * 4);
    int* row_ptr  = (int*)alloc((size_t)(N_NODES + 1) * 4);
    int* cursor   = (int*)alloc((size_t)N_NODES * 4);
    int* csr_src  = (int*)alloc((size_t)N_EDGES * 4);
    float* adp    = (float*)alloc((size_t)N_NODES * 4 * 4);

    int mtiles = (N_NODES + 63) / 64;   // 1563
    int nwaveblocks = N_NODES / 4;      // 25000 (one wave per node, 4 waves/block)

    // CSR build (edges are constant but must be rebuilt every call)
    hipMemsetAsync(cursor, 0, (size_t)N_NODES * 4, stream);
    hist_dst<<<(N_EDGES + 255) / 256, 256, 0, stream>>>(edges, cursor);
    scan_excl<<<1, 1024, 0, stream>>>(cursor, row_ptr);
    copy_int<<<(N_NODES + 255) / 256, 256, 0, stream>>>(row_ptr, cursor, N_NODES);
    scatter_csr<<<(N_EDGES + 255) / 256, 256, 0, stream>>>(edges, cursor, csr_src);

    // node features: gelu(concat(img@Wi+bi, txt@Wt+bt, ars)) scattered via content_indices
    gemm_tiled<1><<<dim3(mtiles, 1), 256, 0, stream>>>(imgf, 512, N_NODES, 512, Wi, 64, bi, node, FEAT, 0, ci);
    gemm_tiled<1><<<dim3(mtiles, 1), 256, 0, stream>>>(txtf, 768, N_NODES, 768, Wt, 64, bt, node, FEAT, 64, ci);
    ars_kernel<<<(N_NODES * 3 + 255) / 256, 256, 0, stream>>>(ars, ci, node);

    // GAT layer 0: h = node @ W0; softmax-aggregate; +b0; relu  -> node buffer (stride 128)
    gemm_tiled<0><<<dim3(mtiles, 2), 256, 0, stream>>>(node, FEAT, N_NODES, FEAT, W0, HID, nullptr, hA, HID, 0, nullptr);
    attn_scores<<<nwaveblocks, 256, 0, stream>>>(hA, as0, ad0, as_buf, ad_buf);
    gat_aggregate<0><<<nwaveblocks, 256, 0, stream>>>(hA, as_buf, ad_buf, row_ptr, csr_src, b0, node);

    // GAT layer 1: h = x @ W1; aggregate; +b1; gelu -> d_out
    gemm_tiled<0><<<dim3(mtiles, 2), 256, 0, stream>>>(node, HID, N_NODES, HID, W1, HID, nullptr, hA, HID, 0, nullptr);
    attn_scores<<<nwaveblocks, 256, 0, stream>>>(hA, as1, ad1, as_buf, ad_buf);
    gat_aggregate<1><<<nwaveblocks, 256, 0, stream>>>(hA, as_buf, ad_buf, row_ptr, csr_src, b1, out0);

    // heads + per-edge predictions
    head_proj<<<nwaveblocks, 256, 0, stream>>>(out0, Wa, ba, Wd, bd, adp);
    edge_pred<<<(N_EDGES + 255) / 256, 256, 0, stream>>>(edges, adp, pred);
}

// Round 2
// 1588.698 us; speedup vs baseline: 1.1548x; 1.1548x over previous
//
#include <hip/hip_runtime.h>
#include <math.h>

#define N_NODES 100000
#define N_EDGES 1600000
#define FEATP 132      // 131 padded to 132 (col 131 = 0, W0 padded with zero row)
#define HID 128

__device__ __forceinline__ float geluf(float x) {
    return 0.5f * x * (1.0f + erff(x * 0.7071067811865475f));
}
__device__ __forceinline__ float leakyf(float x) {
    return x >= 0.0f ? x : 0.2f * x;
}
__device__ __forceinline__ float wave_reduce_max(float v) {
#pragma unroll
    for (int o = 32; o > 0; o >>= 1) v = fmaxf(v, __shfl_xor(v, o, 64));
    return v;
}
__device__ __forceinline__ float wave_reduce_sum(float v) {
#pragma unroll
    for (int o = 32; o > 0; o >>= 1) v += __shfl_xor(v, o, 64);
    return v;
}

// ---------------- GEMM: C[M x N] = act(A[M x K] @ B[K x N] + bias) ----------------
// 128x64 block tile, 256 threads, 8x4 micro-tile, BK=32, register prefetch across
// the barrier. Requires lda%4==0, ldb%4==0, K%4==0, ldc%4==0, colOff%4==0.
// ACT: 0=none, 1=gelu.
template <int ACT>
__global__ __launch_bounds__(256) void gemm128(
    const float* __restrict__ A, int lda, int M, int K,
    const float* __restrict__ B, int ldb,
    const float* __restrict__ bias,
    float* __restrict__ C, int ldc, int colOff,
    const int* __restrict__ rowIdx)
{
    __shared__ float As[32][132];   // [k][m], pad 132: 16B-aligned rows, <=4-way write alias
    __shared__ float Bs[32][64];    // [k][n]
    const int tid = threadIdx.x;
    const int m0 = blockIdx.x * 128;
    const int n0 = blockIdx.y * 64;
    const int tx = tid & 15, ty = tid >> 4;

    const int arow = tid >> 3;        // 0..31 (row within 32-row pass)
    const int acol = (tid & 7) * 4;   // k offset 0..28
    const int brow = tid >> 4;        // 0..15 (k within 16-k pass)
    const int bcol = (tid & 15) * 4;  // n offset 0..60

    float4 pa[4], pb[2];
    const int T = (K + 31) / 32;

    auto fetch = [&](int k0) {
#pragma unroll
        for (int i = 0; i < 4; ++i) {
            int row = m0 + i * 32 + arow;
            int k = k0 + acol;
            pa[i] = (row < M && k < K) ? *(const float4*)&A[(size_t)row * lda + k]
                                       : make_float4(0.f, 0.f, 0.f, 0.f);
        }
#pragma unroll
        for (int i = 0; i < 2; ++i) {
            int k = k0 + i * 16 + brow;
            pb[i] = (k < K) ? *(const float4*)&B[(size_t)k * ldb + n0 + bcol]
                            : make_float4(0.f, 0.f, 0.f, 0.f);
        }
    };

    float acc[8][4] = {};
    fetch(0);
    for (int t = 0; t < T; ++t) {
#pragma unroll
        for (int i = 0; i < 4; ++i) {
            int row = i * 32 + arow;
            As[acol + 0][row] = pa[i].x;
            As[acol + 1][row] = pa[i].y;
            As[acol + 2][row] = pa[i].z;
            As[acol + 3][row] = pa[i].w;
        }
#pragma unroll
        for (int i = 0; i < 2; ++i)
            *(float4*)&Bs[i * 16 + brow][bcol] = pb[i];
        __syncthreads();
        if (t + 1 < T) fetch((t + 1) * 32);   // overlap global latency with compute
#pragma unroll
        for (int kk = 0; kk < 32; ++kk) {
            float4 a0 = *(const float4*)&As[kk][ty * 8];
            float4 a1 = *(const float4*)&As[kk][ty * 8 + 4];
            float4 b  = *(const float4*)&Bs[kk][tx * 4];
            float av[8] = {a0.x, a0.y, a0.z, a0.w, a1.x, a1.y, a1.z, a1.w};
            float bv[4] = {b.x, b.y, b.z, b.w};
#pragma unroll
            for (int i = 0; i < 8; ++i)
#pragma unroll
                for (int j = 0; j < 4; ++j)
                    acc[i][j] = fmaf(av[i], bv[j], acc[i][j]);
        }
        __syncthreads();
    }

#pragma unroll
    for (int i = 0; i < 8; ++i) {
        int row = m0 + ty * 8 + i;
        if (row >= M) continue;
        int orow = rowIdx ? rowIdx[row] : row;
        float4 v;
        float* vp = (float*)&v;
#pragma unroll
        for (int j = 0; j < 4; ++j) {
            float x = acc[i][j];
            if (bias) x += bias[n0 + tx * 4 + j];
            if (ACT == 1) x = geluf(x);
            vp[j] = x;
        }
        *(float4*)&C[(size_t)orow * ldc + colOff + n0 + tx * 4] = v;
    }
}

// node[ci[n]][128+j] = gelu(ars[n][j]) for j<3; node[ci[n]][131] = 0
__global__ void ars_kernel(const float* __restrict__ ars, const int* __restrict__ ci,
                           float* __restrict__ node)
{
    int i = blockIdx.x * blockDim.x + threadIdx.x;
    if (i >= N_NODES * 4) return;
    int n = i >> 2, j = i & 3;
    float v = (j < 3) ? geluf(ars[n * 3 + j]) : 0.0f;
    node[(size_t)ci[n] * FEATP + 128 + j] = v;
}

// W0p[132 x 128]: rows 0..130 copy of W0, row 131 zero
__global__ void pad_W0(const float* __restrict__ W0, float* __restrict__ W0p)
{
    int i = blockIdx.x * blockDim.x + threadIdx.x;
    if (i >= FEATP * HID) return;
    int r = i >> 7;
    W0p[i] = (r < 131) ? W0[i] : 0.0f;
}

// ---------------- CSR build (by dst) ----------------
__global__ void hist_dst(const int* __restrict__ edges, int* __restrict__ deg)
{
    int e = blockIdx.x * blockDim.x + threadIdx.x;
    if (e < N_EDGES) atomicAdd(&deg[edges[2 * e + 1]], 1);
}

__global__ __launch_bounds__(1024) void scan_excl(const int* __restrict__ deg,
                                                  int* __restrict__ row_ptr)
{
    __shared__ int sd[1024];
    int tid = threadIdx.x;
    int base = 0;
    for (int start = 0; start < N_NODES; start += 1024) {
        int i = start + tid;
        int v = (i < N_NODES) ? deg[i] : 0;
        sd[tid] = v;
        __syncthreads();
        for (int off = 1; off < 1024; off <<= 1) {
            int t = (tid >= off) ? sd[tid - off] : 0;
            __syncthreads();
            sd[tid] += t;
            __syncthreads();
        }
        if (i < N_NODES) row_ptr[i] = base + sd[tid] - v;
        base += sd[1023];
        __syncthreads();
    }
    if (tid == 0) row_ptr[N_NODES] = base;
}

__global__ void copy_int(const int* __restrict__ src, int* __restrict__ dst, int n)
{
    int i = blockIdx.x * blockDim.x + threadIdx.x;
    if (i < n) dst[i] = src[i];
}

__global__ void scatter_csr(const int* __restrict__ edges, int* __restrict__ cursor,
                            int* __restrict__ csr_src)
{
    int e = blockIdx.x * blockDim.x + threadIdx.x;
    if (e >= N_EDGES) return;
    int s = edges[2 * e], d = edges[2 * e + 1];
    int pos = atomicAdd(&cursor[d], 1);
    csr_src[pos] = s;
}

// ---------------- attention scalars ----------------
__global__ __launch_bounds__(256) void attn_scores(
    const float* __restrict__ h, const float* __restrict__ atts,
    const float* __restrict__ attd, float* __restrict__ as_, float* __restrict__ ad_)
{
    int lane = threadIdx.x & 63;
    int node = blockIdx.x * 4 + (threadIdx.x >> 6);
    if (node >= N_NODES) return;
    float h0 = h[(size_t)node * HID + lane];
    float h1 = h[(size_t)node * HID + 64 + lane];
    float s = h0 * atts[lane] + h1 * atts[64 + lane];
    float d = h0 * attd[lane] + h1 * attd[64 + lane];
    s = wave_reduce_sum(s);
    d = wave_reduce_sum(d);
    if (lane == 0) { as_[node] = s; ad_[node] = d; }
}

// ---------------- GAT softmax-aggregate, one wave per dst node ----------------
template <int ACT>
__global__ __launch_bounds__(256) void gat_aggregate(
    const float* __restrict__ h,
    const float* __restrict__ as_, const float* __restrict__ ad_,
    const int* __restrict__ row_ptr, const int* __restrict__ csr_src,
    const float* __restrict__ bias, float* __restrict__ outp)
{
    int lane = threadIdx.x & 63;
    int node = blockIdx.x * 4 + (threadIdx.x >> 6);
    if (node >= N_NODES) return;
    int start = row_ptr[node];
    int deg = row_ptr[node + 1] - start;
    float adn = ad_[node];
    float e_self = leakyf(as_[node] + adn);
    float acc0 = 0.0f, acc1 = 0.0f;
    float m, denom;

    if (deg <= 64) {
        int s = 0;
        float e = -INFINITY;
        if (lane < deg) {
            s = csr_src[start + lane];
            e = leakyf(as_[s] + adn);
        }
        m = fmaxf(wave_reduce_max(e), e_self);
        float w = (lane < deg) ? __expf(e - m) : 0.0f;
        denom = wave_reduce_sum(w) + __expf(e_self - m);
        for (int jj = 0; jj < deg; ++jj) {
            int sj = __shfl(s, jj, 64);
            float wj = __shfl(w, jj, 64);
            acc0 += wj * h[(size_t)sj * HID + lane];
            acc1 += wj * h[(size_t)sj * HID + 64 + lane];
        }
    } else {
        float lm = -INFINITY;
        for (int j = lane; j < deg; j += 64)
            lm = fmaxf(lm, leakyf(as_[csr_src[start + j]] + adn));
        m = fmaxf(wave_reduce_max(lm), e_self);
        float lsum = 0.0f;
        for (int j = lane; j < deg; j += 64)
            lsum += __expf(leakyf(as_[csr_src[start + j]] + adn) - m);
        denom = wave_reduce_sum(lsum) + __expf(e_self - m);
        for (int c0 = 0; c0 < deg; c0 += 64) {
            int j = c0 + lane;
            int s = 0;
            float w = 0.0f;
            if (j < deg) {
                s = csr_src[start + j];
                w = __expf(leakyf(as_[s] + adn) - m);
            }
            int cnt = min(64, deg - c0);
            for (int jj = 0; jj < cnt; ++jj) {
                int sj = __shfl(s, jj, 64);
                float wj = __shfl(w, jj, 64);
                acc0 += wj * h[(size_t)sj * HID + lane];
                acc1 += wj * h[(size_t)sj * HID + 64 + lane];
            }
        }
    }

    float wself = __expf(e_self - m);
    acc0 = (acc0 + wself * h[(size_t)node * HID + lane]) / denom;
    acc1 = (acc1 + wself * h[(size_t)node * HID + 64 + lane]) / denom;
    acc0 += bias[lane];
    acc1 += bias[64 + lane];
    if (ACT == 0) {
        acc0 = fmaxf(acc0, 0.0f);
        acc1 = fmaxf(acc1, 0.0f);
    } else {
        acc0 = geluf(acc0);
        acc1 = geluf(acc1);
    }
    outp[(size_t)node * HID + lane] = acc0;
    outp[(size_t)node * HID + 64 + lane] = acc1;
}

// ---------------- heads: pack [a0,a1,d0,d1] per node ----------------
__global__ __launch_bounds__(256) void head_proj(
    const float* __restrict__ outf,
    const float* __restrict__ Wa, const float* __restrict__ ba,
    const float* __restrict__ Wd, const float* __restrict__ bd,
    float* __restrict__ adp)
{
    int lane = threadIdx.x & 63;
    int node = blockIdx.x * 4 + (threadIdx.x >> 6);
    if (node >= N_NODES) return;
    float o0 = outf[(size_t)node * HID + lane];
    float o1 = outf[(size_t)node * HID + 64 + lane];
    float a0 = o0 * Wa[lane * 2] + o1 * Wa[(lane + 64) * 2];
    float a1 = o0 * Wa[lane * 2 + 1] + o1 * Wa[(lane + 64) * 2 + 1];
    float d0 = o0 * Wd[lane * 2] + o1 * Wd[(lane + 64) * 2];
    float d1 = o0 * Wd[lane * 2 + 1] + o1 * Wd[(lane + 64) * 2 + 1];
    a0 = wave_reduce_sum(a0);
    a1 = wave_reduce_sum(a1);
    d0 = wave_reduce_sum(d0);
    d1 = wave_reduce_sum(d1);
    if (lane == 0) {
        float4 v = make_float4(a0 + ba[0], a1 + ba[1], d0 + bd[0], d1 + bd[1]);
        ((float4*)adp)[node] = v;
    }
}

__global__ void edge_pred(const int* __restrict__ edges, const float* __restrict__ adp,
                          float* __restrict__ pred)
{
    int e = blockIdx.x * blockDim.x + threadIdx.x;
    if (e >= N_EDGES) return;
    int s = edges[2 * e], d = edges[2 * e + 1];
    float4 ps = ((const float4*)adp)[s];
    float4 pd = ((const float4*)adp)[d];
    pred[2 * e] = ps.x * pd.x + ps.y * pd.y;
    pred[2 * e + 1] = ps.z * pd.z + ps.w * pd.w;
}

extern "C" void kernel_launch(void* const* d_in, const int* in_sizes, int n_in,
                              void* d_out, int out_size, void* d_ws, size_t ws_size,
                              hipStream_t stream)
{
    const float* imgf = (const float*)d_in[0];
    const float* txtf = (const float*)d_in[1];
    const int* ci     = (const int*)d_in[2];
    // d_in[3] = gt_indices (unused)
    const int* edges  = (const int*)d_in[4];
    const float* ars  = (const float*)d_in[5];
    const float* Wi   = (const float*)d_in[6];
    const float* bi   = (const float*)d_in[7];
    const float* Wt   = (const float*)d_in[8];
    const float* bt   = (const float*)d_in[9];
    const float* W0   = (const float*)d_in[10];
    const float* as0  = (const float*)d_in[11];
    const float* ad0  = (const float*)d_in[12];
    const float* b0   = (const float*)d_in[13];
    const float* W1   = (const float*)d_in[14];
    const float* as1  = (const float*)d_in[15];
    const float* ad1  = (const float*)d_in[16];
    const float* b1   = (const float*)d_in[17];
    const float* Wa   = (const float*)d_in[18];
    const float* ba   = (const float*)d_in[19];
    const float* Wd   = (const float*)d_in[20];
    const float* bd   = (const float*)d_in[21];
    (void)in_sizes; (void)n_in; (void)out_size; (void)ws_size;

    float* out0 = (float*)d_out;                  // N x 128 (gelu'd layer-2 output)
    float* pred = out0 + (size_t)N_NODES * HID;   // E x 2

    char* ws = (char*)d_ws;
    size_t off = 0;
    auto alloc = [&](size_t bytes) -> void* {
        void* p = ws + off;
        off += (bytes + 255) & ~(size_t)255;
        return p;
    };
    float* node   = (float*)alloc((size_t)N_NODES * FEATP * 4); // reused (stride 128) as layer-0 output
    float* hA     = (float*)alloc((size_t)N_NODES * HID * 4);
    float* as_buf = (float*)alloc((size_t)N_NODES * 4);
    float* ad_buf = (float*)alloc((size_t)N_NODES * 4);
    int* row_ptr  = (int*)alloc((size_t)(N_NODES + 1) * 4);
    int* cursor   = (int*)alloc((size_t)N_NODES * 4);
    int* csr_src  = (int*)alloc((size_t)N_EDGES * 4);
    float* adp    = (float*)alloc((size_t)N_NODES * 4 * 4);
    float* W0p    = (float*)alloc((size_t)FEATP * HID * 4);

    int mtiles = (N_NODES + 127) / 128;  // 782
    int nwaveblocks = N_NODES / 4;       // 25000

    // CSR build
    hipMemsetAsync(cursor, 0, (size_t)N_NODES * 4, stream);
    hist_dst<<<(N_EDGES + 255) / 256, 256, 0, stream>>>(edges, cursor);
    scan_excl<<<1, 1024, 0, stream>>>(cursor, row_ptr);
    copy_int<<<(N_NODES + 255) / 256, 256, 0, stream>>>(row_ptr, cursor, N_NODES);
    scatter_csr<<<(N_EDGES + 255) / 256, 256, 0, stream>>>(edges, cursor, csr_src);
    pad_W0<<<(FEATP * HID + 255) / 256, 256, 0, stream>>>(W0, W0p);

    // node features: gelu(concat(img@Wi+bi, txt@Wt+bt, ars)) scattered via content_indices
    gemm128<1><<<dim3(mtiles, 1), 256, 0, stream>>>(imgf, 512, N_NODES, 512, Wi, 64, bi, node, FEATP, 0, ci);
    gemm128<1><<<dim3(mtiles, 1), 256, 0, stream>>>(txtf, 768, N_NODES, 768, Wt, 64, bt, node, FEATP, 64, ci);
    ars_kernel<<<(N_NODES * 4 + 255) / 256, 256, 0, stream>>>(ars, ci, node);

    // GAT layer 0: h = node @ W0p (K=132); aggregate; +b0; relu -> node buffer (stride 128)
    gemm128<0><<<dim3(mtiles, 2), 256, 0, stream>>>(node, FEATP, N_NODES, FEATP, W0p, HID, nullptr, hA, HID, 0, nullptr);
    attn_scores<<<nwaveblocks, 256, 0, stream>>>(hA, as0, ad0, as_buf, ad_buf);
    gat_aggregate<0><<<nwaveblocks, 256, 0, stream>>>(hA, as_buf, ad_buf, row_ptr, csr_src, b0, node);

    // GAT layer 1: h = x @ W1; aggregate; +b1; gelu -> d_out
    gemm128<0><<<dim3(mtiles, 2), 256, 0, stream>>>(node, HID, N_NODES, HID, W1, HID, nullptr, hA, HID, 0, nullptr);
    attn_scores<<<nwaveblocks, 256, 0, stream>>>(hA, as1, ad1, as_buf, ad_buf);
    gat_aggregate<1><<<nwaveblocks, 256, 0, stream>>>(hA, as_buf, ad_buf, row_ptr, csr_src, b1, out0);

    // heads + per-edge predictions
    head_proj<<<nwaveblocks, 256, 0, stream>>>(out0, Wa, ba, Wd, bd, adp);
    edge_pred<<<(N_EDGES + 255) / 256, 256, 0, stream>>>(edges, adp, pred);
}